// Round 14
// baseline (391.042 us; speedup 1.0000x reference)
//
#include <hip/hip_runtime.h>
#include <hip/hip_cooperative_groups.h>

namespace cg = cooperative_groups;

// Problem constants (match reference module)
#define VNX 360
#define VNY 160
#define VNZ 48
#define VC 4
static constexpr int PLANE  = VNZ * VNY * VNX;   // 2,764,800 voxels / batch
static constexpr int NBATCH = 8;
static constexpr int NTH    = 256;
static constexpr int NBLK   = 1024;              // 4 blocks/CU, co-resident
static constexpr int NBP    = 256;               // producer (points) blocks
static constexpr int NBG    = NBLK - NBP;        // consumer (gather) blocks
static constexpr int G4B    = PLANE / 4;         // uint4 groups per batch

typedef unsigned int u32x4 __attribute__((ext_vector_type(4)));
typedef float        f32x4 __attribute__((ext_vector_type(4)));

// ---------------------------------------------------------------------------
// Fused pipeline. R6 retry with the fence bug fixed:
//  - NO acquire fences on consumers (R6's killer: 6144 whole-L2 invalidates).
//    Consumers read winner via agent-scope ATOMIC LOADS -> coherent-point
//    reads; no L2 state to invalidate.
//  - Producers drain vmcnt(0) then release-add done[b].
//  - Init keeps plain cached stores (R13: NT-init regresses).
//  - Output: NT stores (R10: cached regresses). Feats: normal cached loads.
// ---------------------------------------------------------------------------
__global__ __launch_bounds__(NTH, 4)
void vox_fused(const f32x4* __restrict__ pts,
               const int*   __restrict__ bidx,
               unsigned int* __restrict__ winner,
               unsigned int* __restrict__ done,   // [NBATCH], zeroed pre-launch
               float*       __restrict__ out,
               int n)
{
    const int blk = blockIdx.x, tid = threadIdx.x;

    // ---- Phase 0: sentinel init (all blocks, cached stores) ----
    {
        u32x4 s = { ~0u, ~0u, ~0u, ~0u };
        u32x4* w4 = (u32x4*)winner;
        const int total4 = NBATCH * G4B;
        for (int t = blk * NTH + tid; t < total4; t += NBLK * NTH)
            w4[t] = s;
    }
    cg::this_grid().sync();

    const unsigned int un = (unsigned int)n;

    if (blk < NBP) {
        // ------------------- producer: points role -------------------
        __shared__ int bnd[NBATCH + 1];
        if (tid <= NBATCH) {               // batch boundaries (sorted bidx)
            int b = tid, lo = 0, hi = n;
            if (b == 0)           lo = 0;
            else if (b == NBATCH) lo = n;
            else {
                while (lo < hi) { int m = (lo + hi) >> 1;
                                  if (bidx[m] < b) lo = m + 1; else hi = m; }
            }
            bnd[b] = lo;
        }
        __syncthreads();

        for (int b = 0; b < NBATCH; ++b) {
            int lo = bnd[b], hi = bnd[b + 1];
            for (int i = lo + blk * NTH + tid; i < hi; i += NBP * NTH) {
                f32x4 p = pts[i];
                // (p - lo) * 5.0f — matches XLA-CPU fast-math reciprocal
                // rewrite of /0.2f; verified bit-exact (round 4).
                int xi = (int)floorf(p.x * 5.0f);
                int yi = (int)floorf((p.y + 16.0f) * 5.0f);
                int zi = (int)floorf((p.z +  2.0f) * 5.0f);
                if ((unsigned)xi < VNX && (unsigned)yi < VNY && (unsigned)zi < VNZ) {
                    int flat = ((b * VNZ + zi) * VNY + yi) * VNX + xi;
                    atomicMin(&winner[flat], (unsigned int)i);
                }
            }
            // All this wave's atomics committed at the coherent point:
            asm volatile("s_waitcnt vmcnt(0)" ::: "memory");
            __syncthreads();               // whole block done with batch b
            if (tid == 0)
                __hip_atomic_fetch_add(&done[b], 1u, __ATOMIC_RELEASE,
                                       __HIP_MEMORY_SCOPE_AGENT);
        }
    } else {
        // ------------------- consumer: gather role -------------------
        const int cblk = blk - NBP;
        const f32x4 zero = { 0.f, 0.f, 0.f, 0.f };

        for (int b = 0; b < NBATCH; ++b) {
            if (tid == 0) {                // wait: batch b fully scattered
                while (__hip_atomic_load(&done[b], __ATOMIC_RELAXED,
                                         __HIP_MEMORY_SCOPE_AGENT) < (unsigned)NBP)
                    __builtin_amdgcn_s_sleep(8);
            }
            __syncthreads();               // NO L2-invalidating fence here

            const unsigned long long* wb =
                (const unsigned long long*)(winner + (size_t)b * PLANE);
            float* obase = out + (size_t)b * (VC * (size_t)PLANE);

            for (int g = cblk * NTH + tid; g < G4B; g += NBG * NTH) {
                // coherent-point reads of 4 winners (2 x 8B agent atomics)
                unsigned long long w01 = __hip_atomic_load(&wb[2 * g + 0],
                        __ATOMIC_RELAXED, __HIP_MEMORY_SCOPE_AGENT);
                unsigned long long w23 = __hip_atomic_load(&wb[2 * g + 1],
                        __ATOMIC_RELAXED, __HIP_MEMORY_SCOPE_AGENT);
                unsigned w0 = (unsigned)w01, w1 = (unsigned)(w01 >> 32);
                unsigned w2 = (unsigned)w23, w3 = (unsigned)(w23 >> 32);

                f32x4 f0 = (w0 < un) ? pts[w0] : zero;
                f32x4 f1 = (w1 < un) ? pts[w1] : zero;
                f32x4 f2 = (w2 < un) ? pts[w2] : zero;
                f32x4 f3 = (w3 < un) ? pts[w3] : zero;

                float* base = obase + (size_t)g * 4;
                f32x4 c0 = { f0.x, f1.x, f2.x, f3.x };
                f32x4 c1 = { f0.y, f1.y, f2.y, f3.y };
                f32x4 c2 = { f0.z, f1.z, f2.z, f3.z };
                f32x4 c3 = { f0.w, f1.w, f2.w, f3.w };
                __builtin_nontemporal_store(c0, (f32x4*)(base + 0 * (size_t)PLANE));
                __builtin_nontemporal_store(c1, (f32x4*)(base + 1 * (size_t)PLANE));
                __builtin_nontemporal_store(c2, (f32x4*)(base + 2 * (size_t)PLANE));
                __builtin_nontemporal_store(c3, (f32x4*)(base + 3 * (size_t)PLANE));
            }
        }
    }
}

// ---------------------------------------------------------------------------
extern "C" void kernel_launch(void* const* d_in, const int* in_sizes, int n_in,
                              void* d_out, int out_size, void* d_ws, size_t ws_size,
                              hipStream_t stream) {
    const f32x4* pts  = (const f32x4*)d_in[0];   // [N,4] f32
    const int*   bidx = (const int*)d_in[1];     // [N] int32, sorted
    int n = in_sizes[1];

    int G = out_size / VC;                       // NBATCH * PLANE

    unsigned int* winner = (unsigned int*)d_ws;                  // 88.5 MB
    unsigned int* done   = (unsigned int*)((char*)d_ws +
                              (size_t)G * sizeof(unsigned int)); // 8 counters

    // Zero the done flags (stream-ordered before the cooperative launch).
    hipMemsetAsync(done, 0, NBATCH * sizeof(unsigned int), stream);

    float* out = (float*)d_out;
    void* args[] = { (void*)&pts, (void*)&bidx, (void*)&winner,
                     (void*)&done, (void*)&out, (void*)&n };
    hipLaunchCooperativeKernel((const void*)vox_fused,
                               dim3(NBLK), dim3(NTH), args, 0, stream);
}

// Round 15
// 161.108 us; speedup vs baseline: 2.4272x; 2.4272x over previous
//
#include <hip/hip_runtime.h>

// Problem constants (match reference module)
#define VNX 360
#define VNY 160
#define VNZ 48
#define VC 4
static constexpr int PLANE = VNZ * VNY * VNX;   // 2,764,800 voxels per batch

typedef unsigned int u32x4 __attribute__((ext_vector_type(4)));
typedef float        f32x4 __attribute__((ext_vector_type(4)));

// ---------------------------------------------------------------------------
// FINAL CONFIG (= R11, best measured: 160.3 us). Verdict table from the
// search:
//   init:   hipMemsetAsync (cached fill)  [NT-init +32us (R13); hand-rolled
//           grid-stride == memset (R11)]
//   points: plain per-point atomicMin     [measured 62us via double-dispatch
//           A/B (R12); atomic-throughput-bound, insensitive to sentinel
//           cache state (R12/R13)]
//   gather: grid-stride 2048, NT winner loads, NT out stores
//           [cached out stores +31us (R10); adjacent unroll +44us (R8);
//           MLP-doubling unroll neutral (R9) -> not latency-bound]
//   fusion: dead (R6: 610us acquire-fence L2 thrash; R14: 391us uncached
//           coherent winner reads). Kernel-boundary flush is the cheapest
//           coherence mechanism for atomic->load visibility.
// ---------------------------------------------------------------------------

// Pass 2: per-point voxelization, first-point-wins via atomicMin(pid).
// Binning: (p - lo) * 5.0f (NOT /0.2f) — matches XLA-CPU fast-math
// reciprocal rewrite of the reference's /0.2f; verified bit-exact (R4).
__global__ void vox_points_kernel(const float4* __restrict__ pts,
                                  const int* __restrict__ bidx,
                                  unsigned int* __restrict__ winner,
                                  int n) {
    int i = blockIdx.x * blockDim.x + threadIdx.x;
    if (i >= n) return;

    float4 p = pts[i];  // x, y, z, power
    int xi = (int)floorf((p.x -  0.0f) * 5.0f);
    int yi = (int)floorf((p.y + 16.0f) * 5.0f);
    int zi = (int)floorf((p.z +  2.0f) * 5.0f);

    if ((unsigned)xi >= VNX || (unsigned)yi >= VNY || (unsigned)zi >= VNZ)
        return;

    int b = bidx[i];
    int flat = ((b * VNZ + zi) * VNY + yi) * VNX + xi;
    atomicMin(&winner[flat], (unsigned int)i);
}

// Pass 3: gather + transpose to [B, C, Z, Y, X].
__global__ void vox_gather_kernel(const u32x4* __restrict__ winner4,
                                  const f32x4* __restrict__ feats,
                                  float* __restrict__ out,
                                  unsigned int n, int nvox4) {
    int stride = gridDim.x * blockDim.x;
    const f32x4 zero = { 0.f, 0.f, 0.f, 0.f };

    for (int t = blockIdx.x * blockDim.x + threadIdx.x; t < nvox4; t += stride) {
        u32x4 w = __builtin_nontemporal_load(&winner4[t]);

        f32x4 f0 = (w.x < n) ? feats[w.x] : zero;
        f32x4 f1 = (w.y < n) ? feats[w.y] : zero;
        f32x4 f2 = (w.z < n) ? feats[w.z] : zero;
        f32x4 f3 = (w.w < n) ? feats[w.w] : zero;

        int v = t * 4;                   // 4 consecutive voxels, same batch
        int b = v / PLANE;               // PLANE % 4 == 0
        int r = v - b * PLANE;
        float* base = out + (size_t)b * (VC * (size_t)PLANE) + r;

        f32x4 c0 = { f0.x, f1.x, f2.x, f3.x };
        f32x4 c1 = { f0.y, f1.y, f2.y, f3.y };
        f32x4 c2 = { f0.z, f1.z, f2.z, f3.z };
        f32x4 c3 = { f0.w, f1.w, f2.w, f3.w };
        __builtin_nontemporal_store(c0, (f32x4*)(base + 0 * (size_t)PLANE));
        __builtin_nontemporal_store(c1, (f32x4*)(base + 1 * (size_t)PLANE));
        __builtin_nontemporal_store(c2, (f32x4*)(base + 2 * (size_t)PLANE));
        __builtin_nontemporal_store(c3, (f32x4*)(base + 3 * (size_t)PLANE));
    }
}

// ---------------------------------------------------------------------------
extern "C" void kernel_launch(void* const* d_in, const int* in_sizes, int n_in,
                              void* d_out, int out_size, void* d_ws, size_t ws_size,
                              hipStream_t stream) {
    const float* rdr  = (const float*)d_in[0];   // [N,4] f32
    const int*   bidx = (const int*)d_in[1];     // [N] int32 on device
    int n = in_sizes[1];

    int G  = out_size / VC;                      // 22,118,400 voxels
    int n4 = G / 4;                              // winner uint4 count

    unsigned int* winner = (unsigned int*)d_ws;  // 88.5 MB (ws is ~1.4 GB)

    int block = 256;
    int grid_dense = 2048;                       // grid-stride, 8 blocks/CU

    // Pass 1: sentinel init (rocclr fill, 6.7-6.9 TB/s measured)
    hipMemsetAsync(winner, 0xFF, (size_t)G * sizeof(unsigned int), stream);

    // Pass 2: scatter min point-id per voxel
    vox_points_kernel<<<(n + block - 1) / block, block, 0, stream>>>(
        (const float4*)rdr, bidx, winner, n);

    // Pass 3: gather + channel transpose
    vox_gather_kernel<<<grid_dense, block, 0, stream>>>(
        (const u32x4*)winner, (const f32x4*)rdr, (float*)d_out,
        (unsigned int)n, n4);
}